// Round 5
// baseline (671.509 us; speedup 1.0000x reference)
//
#include <hip/hip_runtime.h>

#define D_MODEL 1024
#define S_LEN   2048
#define BATCH   4
#define NH      16
#define DH      64
#define M_ROWS  (BATCH * S_LEN)   // 8192

typedef __attribute__((ext_vector_type(8))) short short8;
typedef __attribute__((ext_vector_type(4))) float floatx4;
typedef unsigned short ushort_t;
typedef __attribute__((ext_vector_type(4))) ushort_t ushortx4;

__device__ __forceinline__ float bf2f(ushort_t h) {
    union { unsigned u; float f; } v; v.u = ((unsigned)h) << 16; return v.f;
}
__device__ __forceinline__ ushort_t f2bf(float f) {
    union { float f; unsigned u; } v; v.f = f;
    unsigned r = v.u + 0x7FFFu + ((v.u >> 16) & 1u);
    return (ushort_t)(r >> 16);
}

// ---------------------------------------------------------------------------
// fp32 -> bf16 downcast of x, W_qkv, W_o into workspace. 4 elems / thread.
// ---------------------------------------------------------------------------
#define N0 (M_ROWS * D_MODEL)        // x:      8,388,608
#define N1 (3 * D_MODEL * D_MODEL)   // W_qkv:  3,145,728
#define N2 (D_MODEL * D_MODEL)       // W_o:    1,048,576
#define NQUADS ((N0 + N1 + N2) / 4)

__global__ __launch_bounds__(256)
void cvt_f32_bf16(const float* __restrict__ s0, const float* __restrict__ s1,
                  const float* __restrict__ s2, ushort_t* __restrict__ d0,
                  ushort_t* __restrict__ d1, ushort_t* __restrict__ d2)
{
    const int q = blockIdx.x * 256 + threadIdx.x;
    if (q >= NQUADS) return;
    const float* s; ushort_t* d; int e;
    if (q < N0 / 4)            { s = s0; d = d0; e = q * 4; }
    else if (q < (N0 + N1) / 4){ s = s1; d = d1; e = q * 4 - N0; }
    else                       { s = s2; d = d2; e = q * 4 - N0 - N1; }
    const float4 v = *(const float4*)&s[e];
    ushortx4 o;
    o[0] = f2bf(v.x); o[1] = f2bf(v.y); o[2] = f2bf(v.z); o[3] = f2bf(v.w);
    *(ushortx4*)&d[e] = o;
}

// ---------------------------------------------------------------------------
// NT GEMM: C[M,N] = A[M,K] * B[N,K]^T + bias[N]. A,B bf16; bias fp32; fp32 acc.
// VSPLIT (QKV gemm): cols [0,2048) -> qk[row*2048+col] bf16;
//                    cols [2048,3072) -> vt[b][h][dh][s] bf16 (V transposed).
// else: Cv with stride N, bf16 or fp32 per F32OUT.
// ---------------------------------------------------------------------------
template<bool F32OUT, bool VSPLIT>
__global__ __launch_bounds__(256)
void gemm_bt_bias(const ushort_t* __restrict__ A, const ushort_t* __restrict__ B,
                  const float* __restrict__ bias, void* __restrict__ Cv,
                  ushort_t* __restrict__ vt, int M, int N, int K)
{
    constexpr int BK = 32, PAD = 8;
    __shared__ ushort_t As[128][BK + PAD];
    __shared__ ushort_t Bs[128][BK + PAD];

    const int tid  = threadIdx.x;
    const int lane = tid & 63;
    const int wave = tid >> 6;
    const int quad = lane >> 4;
    const int l16  = lane & 15;
    const int bm   = blockIdx.y * 128;
    const int bn   = blockIdx.x * 128;
    const int wm   = (wave & 1) * 64;
    const int wn   = (wave >> 1) * 64;

    floatx4 acc[4][4] = {};

    const int r0 = tid >> 2;
    const int c0 = (tid & 3) * 8;

    for (int k0 = 0; k0 < K; k0 += BK) {
        __syncthreads();
        *(short8*)&As[r0][c0]      = *(const short8*)&A[(size_t)(bm + r0)      * K + k0 + c0];
        *(short8*)&As[r0 + 64][c0] = *(const short8*)&A[(size_t)(bm + r0 + 64) * K + k0 + c0];
        *(short8*)&Bs[r0][c0]      = *(const short8*)&B[(size_t)(bn + r0)      * K + k0 + c0];
        *(short8*)&Bs[r0 + 64][c0] = *(const short8*)&B[(size_t)(bn + r0 + 64) * K + k0 + c0];
        __syncthreads();

        short8 af[4], bfr[4];
        #pragma unroll
        for (int i = 0; i < 4; i++) af[i]  = *(const short8*)&As[wm + i * 16 + l16][quad * 8];
        #pragma unroll
        for (int i = 0; i < 4; i++) bfr[i] = *(const short8*)&Bs[wn + i * 16 + l16][quad * 8];

        #pragma unroll
        for (int mi = 0; mi < 4; mi++)
            #pragma unroll
            for (int ni = 0; ni < 4; ni++)
                acc[mi][ni] = __builtin_amdgcn_mfma_f32_16x16x32_bf16(af[mi], bfr[ni], acc[mi][ni], 0, 0, 0);
    }

    // Epilogue: C/D layout col = lane&15, row = quad*4 + reg
    #pragma unroll
    for (int ni = 0; ni < 4; ni++) {
        const int col = bn + wn + ni * 16 + l16;
        const float bv = bias[col];
        #pragma unroll
        for (int mi = 0; mi < 4; mi++)
            #pragma unroll
            for (int r = 0; r < 4; r++) {
                const int row = bm + wm + mi * 16 + quad * 4 + r;
                const float val = acc[mi][ni][r] + bv;
                if (VSPLIT) {
                    if (col < 2 * D_MODEL) {   // block-uniform branch
                        ((ushort_t*)Cv)[(size_t)row * 2048 + col] = f2bf(val);
                    } else {
                        const int vcol = col - 2 * D_MODEL;
                        const int h = vcol >> 6, dh = vcol & 63;
                        const int b = row >> 11, s = row & 2047;
                        vt[(((size_t)(b * NH + h)) * DH + dh) * S_LEN + s] = f2bf(val);
                    }
                } else if (F32OUT) {
                    ((float*)Cv)[(size_t)row * N + col] = val;
                } else {
                    ((ushort_t*)Cv)[(size_t)row * N + col] = f2bf(val);
                }
            }
    }
}

// ---------------------------------------------------------------------------
// Causal flash attention, barrier-free.
// qk: [B, S, 2048] (Q | K per row, bf16). vt: [B,H,DH,S] (V transposed, bf16).
// Block = one (b,h) x 64 q rows; 4 waves x 16 q rows; BKV=128 key tiles.
// K and V^T B-fragments load straight from global (16B/lane, L1/L2-hit).
// Only LDS use: per-wave P C-layout -> A-layout round-trip (no barriers).
// out: [B, S, D_MODEL] bf16.
// ---------------------------------------------------------------------------
#define BQ  64
#define BKV 128

__global__ __launch_bounds__(256, 4)
void attn_causal(const ushort_t* __restrict__ qk, const ushort_t* __restrict__ vt,
                 ushort_t* __restrict__ out)
{
    __shared__ ushort_t Ps[4][16][BKV + 8];   // row stride 136 elems (272B)

    const int tid  = threadIdx.x;
    const int lane = tid & 63;
    const int wave = tid >> 6;
    const int quad = lane >> 4;
    const int l16  = lane & 15;

    const int qt = blockIdx.x;
    const int bh = blockIdx.y;
    const int b  = bh >> 4;
    const int h  = bh & 15;
    const int q0 = qt * BQ;

    const size_t qkbase = (size_t)b * S_LEN * 2048;
    // Q A-fragment straight from global: A[m=l16][k=quad*8+j]
    const ushort_t* qptr = qk + qkbase + (size_t)(q0 + wave * 16 + l16) * 2048 + h * DH;
    const short8 qf0 = *(const short8*)(qptr + quad * 8);
    const short8 qf1 = *(const short8*)(qptr + 32 + quad * 8);

    const ushort_t* kbase = qk + qkbase + D_MODEL + h * DH;          // + key*2048
    const ushort_t* vbase = vt + ((size_t)(b * NH + h) * DH) * S_LEN; // + dh*S + s

    float m_run[4], l_run[4];
    floatx4 o_acc[4] = {};
    #pragma unroll
    for (int r = 0; r < 4; r++) { m_run[r] = -1e30f; l_run[r] = 0.f; }

    const int ntiles = (q0 + BQ + BKV - 1) / BKV;
    for (int t = 0; t < ntiles; t++) {
        const int kb = t * BKV;

        // ---- S = Q K^T : scores row = quad*4+reg, col = kb + ns*16 + l16
        floatx4 sc[8];
        #pragma unroll
        for (int ns = 0; ns < 8; ns++) {
            const ushort_t* kp = kbase + (size_t)(kb + ns * 16 + l16) * 2048 + quad * 8;
            const short8 kf0 = *(const short8*)kp;
            const short8 kf1 = *(const short8*)(kp + 32);
            floatx4 z = {};
            z = __builtin_amdgcn_mfma_f32_16x16x32_bf16(qf0, kf0, z, 0, 0, 0);
            z = __builtin_amdgcn_mfma_f32_16x16x32_bf16(qf1, kf1, z, 0, 0, 0);
            sc[ns] = z;
        }

        // ---- scale + (conditional) causal mask + row max
        const bool need_mask = (kb + BKV > q0);   // wave-uniform
        float mt[4];
        #pragma unroll
        for (int r = 0; r < 4; r++) {
            const int qi = q0 + wave * 16 + quad * 4 + r;
            float mx = -1e30f;
            #pragma unroll
            for (int ns = 0; ns < 8; ns++) {
                float v = sc[ns][r] * 0.125f;
                if (need_mask) {
                    const int kj = kb + ns * 16 + l16;
                    v = (kj <= qi) ? v : -1e30f;
                }
                sc[ns][r] = v;
                mx = fmaxf(mx, v);
            }
            mt[r] = mx;
        }
        #pragma unroll
        for (int off = 1; off < 16; off <<= 1)
            #pragma unroll
            for (int r = 0; r < 4; r++)
                mt[r] = fmaxf(mt[r], __shfl_xor(mt[r], off, 64));

        // ---- online softmax
        float alpha[4], rs[4];
        #pragma unroll
        for (int r = 0; r < 4; r++) {
            const float mnew = fmaxf(m_run[r], mt[r]);
            alpha[r] = __expf(m_run[r] - mnew);
            m_run[r] = mnew;
            float s = 0.f;
            #pragma unroll
            for (int ns = 0; ns < 8; ns++) {
                const float p = __expf(sc[ns][r] - mnew);
                sc[ns][r] = p;
                s += p;
            }
            rs[r] = s;
        }
        #pragma unroll
        for (int off = 1; off < 16; off <<= 1)
            #pragma unroll
            for (int r = 0; r < 4; r++)
                rs[r] += __shfl_xor(rs[r], off, 64);
        #pragma unroll
        for (int r = 0; r < 4; r++) l_run[r] = l_run[r] * alpha[r] + rs[r];

        // ---- P: C-layout -> per-wave LDS -> A-layout (same-wave RAW, in-order DS)
        #pragma unroll
        for (int ns = 0; ns < 8; ns++)
            #pragma unroll
            for (int r = 0; r < 4; r++)
                Ps[wave][quad * 4 + r][ns * 16 + l16] = f2bf(sc[ns][r]);

        #pragma unroll
        for (int d = 0; d < 4; d++)
            #pragma unroll
            for (int r = 0; r < 4; r++)
                o_acc[d][r] *= alpha[r];

        short8 pf[4];
        #pragma unroll
        for (int c = 0; c < 4; c++)
            pf[c] = *(const short8*)&Ps[wave][l16][c * 32 + quad * 8];

        // ---- O += P V  (V^T B-fragments straight from global)
        #pragma unroll
        for (int d = 0; d < 4; d++) {
            const ushort_t* vp = vbase + (size_t)(d * 16 + l16) * S_LEN + kb + quad * 8;
            #pragma unroll
            for (int c = 0; c < 4; c++) {
                const short8 vf = *(const short8*)(vp + c * 32);
                o_acc[d] = __builtin_amdgcn_mfma_f32_16x16x32_bf16(pf[c], vf, o_acc[d], 0, 0, 0);
            }
        }
    }

    // ---- out[b, qi, h*64 + dh] = o / l
    #pragma unroll
    for (int r = 0; r < 4; r++) {
        const float inv = 1.0f / l_run[r];
        const int qi = q0 + wave * 16 + quad * 4 + r;
        #pragma unroll
        for (int d = 0; d < 4; d++)
            out[(size_t)(b * S_LEN + qi) * D_MODEL + h * DH + d * 16 + l16] =
                f2bf(o_acc[d][r] * inv);
    }
}

// ---------------------------------------------------------------------------
extern "C" void kernel_launch(void* const* d_in, const int* in_sizes, int n_in,
                              void* d_out, int out_size, void* d_ws, size_t ws_size,
                              hipStream_t stream)
{
    const float* x    = (const float*)d_in[0];
    const float* Wqkv = (const float*)d_in[1];
    const float* bqkv = (const float*)d_in[2];
    const float* Wo   = (const float*)d_in[3];
    const float* bo   = (const float*)d_in[4];
    float* out = (float*)d_out;

    ushort_t* xb    = (ushort_t*)d_ws;                       // N0
    ushort_t* wqkvb = xb + N0;                               // N1
    ushort_t* wob   = wqkvb + N1;                            // N2
    ushort_t* qkbuf = wob + N2;                              // 8192*2048
    ushort_t* vtbuf = qkbuf + (size_t)M_ROWS * 2048;         // B*NH*DH*S
    ushort_t* att   = vtbuf + (size_t)BATCH * NH * DH * S_LEN; // 8192*1024
    // total = 92.3 MB

    dim3 blk(256);
    cvt_f32_bf16<<<dim3((NQUADS + 255) / 256), blk, 0, stream>>>(x, Wqkv, Wo, xb, wqkvb, wob);
    // QKV projection: M=8192, N=3072, K=1024 -> qk (packed Q|K) + vt (V^T)
    gemm_bt_bias<false, true><<<dim3((3 * D_MODEL) / 128, M_ROWS / 128), blk, 0, stream>>>(
        xb, wqkvb, bqkv, qkbuf, vtbuf, M_ROWS, 3 * D_MODEL, D_MODEL);
    // causal attention (barrier-free)
    attn_causal<<<dim3(S_LEN / BQ, BATCH * NH), blk, 0, stream>>>(qkbuf, vtbuf, att);
    // output projection: M=8192, N=1024, K=1024 -> fp32 d_out
    gemm_bt_bias<true, false><<<dim3(D_MODEL / 128, M_ROWS / 128), blk, 0, stream>>>(
        att, wob, bo, out, nullptr, M_ROWS, D_MODEL, D_MODEL);
}

// Round 6
// 393.035 us; speedup vs baseline: 1.7085x; 1.7085x over previous
//
#include <hip/hip_runtime.h>

#define D_MODEL 1024
#define S_LEN   2048
#define BATCH   4
#define NH      16
#define DH      64
#define M_ROWS  (BATCH * S_LEN)   // 8192

typedef __attribute__((ext_vector_type(8))) short short8;
typedef __attribute__((ext_vector_type(4))) float floatx4;
typedef unsigned short ushort_t;
typedef __attribute__((ext_vector_type(4))) ushort_t ushortx4;

__device__ __forceinline__ float bf2f(ushort_t h) {
    union { unsigned u; float f; } v; v.u = ((unsigned)h) << 16; return v.f;
}
__device__ __forceinline__ ushort_t f2bf(float f) {
    union { float f; unsigned u; } v; v.f = f;
    unsigned r = v.u + 0x7FFFu + ((v.u >> 16) & 1u);
    return (ushort_t)(r >> 16);
}

// ---------------------------------------------------------------------------
// fp32 -> bf16 downcast of x, W_qkv, W_o into workspace. 4 elems / thread.
// ---------------------------------------------------------------------------
#define N0 (M_ROWS * D_MODEL)        // x:      8,388,608
#define N1 (3 * D_MODEL * D_MODEL)   // W_qkv:  3,145,728
#define N2 (D_MODEL * D_MODEL)       // W_o:    1,048,576
#define NQUADS ((N0 + N1 + N2) / 4)

__global__ __launch_bounds__(256)
void cvt_f32_bf16(const float* __restrict__ s0, const float* __restrict__ s1,
                  const float* __restrict__ s2, ushort_t* __restrict__ d0,
                  ushort_t* __restrict__ d1, ushort_t* __restrict__ d2)
{
    const int q = blockIdx.x * 256 + threadIdx.x;
    if (q >= NQUADS) return;
    const float* s; ushort_t* d; int e;
    if (q < N0 / 4)            { s = s0; d = d0; e = q * 4; }
    else if (q < (N0 + N1) / 4){ s = s1; d = d1; e = q * 4 - N0; }
    else                       { s = s2; d = d2; e = q * 4 - N0 - N1; }
    const float4 v = *(const float4*)&s[e];
    ushortx4 o;
    o[0] = f2bf(v.x); o[1] = f2bf(v.y); o[2] = f2bf(v.z); o[3] = f2bf(v.w);
    *(ushortx4*)&d[e] = o;
}

// ---------------------------------------------------------------------------
// NT GEMM: C[M,N] = A[M,K] * B[N,K]^T + bias[N]. A,B bf16; bias fp32; fp32 acc.
// VSPLIT (QKV gemm): cols [0,2048) -> qk[row*2048+col] bf16;
//                    cols [2048,3072) -> vt[b][h][dh][s] bf16 (V transposed).
// else: Cv with stride N, bf16 or fp32 per F32OUT.
// ---------------------------------------------------------------------------
template<bool F32OUT, bool VSPLIT>
__global__ __launch_bounds__(256)
void gemm_bt_bias(const ushort_t* __restrict__ A, const ushort_t* __restrict__ B,
                  const float* __restrict__ bias, void* __restrict__ Cv,
                  ushort_t* __restrict__ vt, int M, int N, int K)
{
    constexpr int BK = 32, PAD = 8;
    __shared__ ushort_t As[128][BK + PAD];
    __shared__ ushort_t Bs[128][BK + PAD];

    const int tid  = threadIdx.x;
    const int lane = tid & 63;
    const int wave = tid >> 6;
    const int quad = lane >> 4;
    const int l16  = lane & 15;
    const int bm   = blockIdx.y * 128;
    const int bn   = blockIdx.x * 128;
    const int wm   = (wave & 1) * 64;
    const int wn   = (wave >> 1) * 64;

    floatx4 acc[4][4] = {};

    const int r0 = tid >> 2;
    const int c0 = (tid & 3) * 8;

    for (int k0 = 0; k0 < K; k0 += BK) {
        __syncthreads();
        *(short8*)&As[r0][c0]      = *(const short8*)&A[(size_t)(bm + r0)      * K + k0 + c0];
        *(short8*)&As[r0 + 64][c0] = *(const short8*)&A[(size_t)(bm + r0 + 64) * K + k0 + c0];
        *(short8*)&Bs[r0][c0]      = *(const short8*)&B[(size_t)(bn + r0)      * K + k0 + c0];
        *(short8*)&Bs[r0 + 64][c0] = *(const short8*)&B[(size_t)(bn + r0 + 64) * K + k0 + c0];
        __syncthreads();

        short8 af[4], bfr[4];
        #pragma unroll
        for (int i = 0; i < 4; i++) af[i]  = *(const short8*)&As[wm + i * 16 + l16][quad * 8];
        #pragma unroll
        for (int i = 0; i < 4; i++) bfr[i] = *(const short8*)&Bs[wn + i * 16 + l16][quad * 8];

        #pragma unroll
        for (int mi = 0; mi < 4; mi++)
            #pragma unroll
            for (int ni = 0; ni < 4; ni++)
                acc[mi][ni] = __builtin_amdgcn_mfma_f32_16x16x32_bf16(af[mi], bfr[ni], acc[mi][ni], 0, 0, 0);
    }

    // Epilogue: C/D layout col = lane&15, row = quad*4 + reg
    #pragma unroll
    for (int ni = 0; ni < 4; ni++) {
        const int col = bn + wn + ni * 16 + l16;
        const float bv = bias[col];
        #pragma unroll
        for (int mi = 0; mi < 4; mi++)
            #pragma unroll
            for (int r = 0; r < 4; r++) {
                const int row = bm + wm + mi * 16 + quad * 4 + r;
                const float val = acc[mi][ni][r] + bv;
                if (VSPLIT) {
                    if (col < 2 * D_MODEL) {   // block-uniform branch
                        ((ushort_t*)Cv)[(size_t)row * 2048 + col] = f2bf(val);
                    } else {
                        const int vcol = col - 2 * D_MODEL;
                        const int h = vcol >> 6, dh = vcol & 63;
                        const int b = row >> 11, s = row & 2047;
                        vt[(((size_t)(b * NH + h)) * DH + dh) * S_LEN + s] = f2bf(val);
                    }
                } else if (F32OUT) {
                    ((float*)Cv)[(size_t)row * N + col] = val;
                } else {
                    ((ushort_t*)Cv)[(size_t)row * N + col] = f2bf(val);
                }
            }
    }
}

// ---------------------------------------------------------------------------
// Causal flash attention, LDS-staged + register-prefetch pipeline.
// qk: [B, S, 2048] (Q | K packed, bf16). vt: [B,H,DH,S] (V transposed, bf16).
// Block = one (b,h) x 128 q rows; 4 waves x 32 q rows (2 m-frags, processed
// sequentially to cap VGPRs); BKV=128 key tiles.
// Pipeline: prefetch tile t+1 K/V into regs right after staging barrier ->
// global latency hidden behind tile t compute.
// Row sums via MFMA against a ones-fragment (no shuffle tree for l).
// out: [B, S, D_MODEL] bf16.
// ---------------------------------------------------------------------------
#define BQ  128
#define BKV 128

__global__ __launch_bounds__(256, 2)
void attn_causal(const ushort_t* __restrict__ qk, const ushort_t* __restrict__ vt,
                 ushort_t* __restrict__ out)
{
    __shared__ ushort_t Ks[BKV][DH + 8];      // [key][dh]   stride 144B  (18.4 KB)
    __shared__ ushort_t Vs[DH][BKV + 8];      // [dh][key]   stride 272B  (17.4 KB)
    __shared__ ushort_t Ps[4][16][BKV + 8];   // per-wave P  stride 272B  (17.4 KB)

    const int tid  = threadIdx.x;
    const int lane = tid & 63;
    const int wave = tid >> 6;
    const int quad = lane >> 4;
    const int l16  = lane & 15;

    const int qt = (int)gridDim.x - 1 - (int)blockIdx.x;   // heavy blocks first (LPT)
    const int bh = blockIdx.y;
    const int b  = bh >> 4;
    const int h  = bh & 15;
    const int q0 = qt * BQ;

    const size_t qkbase = (size_t)b * S_LEN * 2048;

    // Q A-fragments straight from global: A[m=l16][k=quad*8+j]
    short8 qf[2][2];
    #pragma unroll
    for (int mi = 0; mi < 2; mi++) {
        const ushort_t* qp = qk + qkbase + (size_t)(q0 + wave * 32 + mi * 16 + l16) * 2048 + h * DH;
        qf[mi][0] = *(const short8*)(qp + quad * 8);
        qf[mi][1] = *(const short8*)(qp + 32 + quad * 8);
    }

    const ushort_t* kg = qk + qkbase + D_MODEL + h * DH;            // + key*2048
    const ushort_t* vg = vt + (size_t)(b * NH + h) * DH * S_LEN;    // + dh*S + key

    // staging map: K 8 thr/row (128B), V 16 thr/row (256B) — fully coalesced
    const int krow = tid >> 3, kcol = (tid & 7) * 8;
    const int vrow = tid >> 4, vcol = (tid & 15) * 8;

    short8 kreg[4], vreg[4];
    #pragma unroll
    for (int p = 0; p < 4; p++) {
        kreg[p] = *(const short8*)&kg[(size_t)(p * 32 + krow) * 2048 + kcol];
        vreg[p] = *(const short8*)&vg[(size_t)(p * 16 + vrow) * S_LEN + vcol];
    }

    float m_run[2][4], l_run[2][4];
    floatx4 o_acc[2][4] = {};
    #pragma unroll
    for (int mi = 0; mi < 2; mi++)
        #pragma unroll
        for (int r = 0; r < 4; r++) { m_run[mi][r] = -1e30f; l_run[mi][r] = 0.f; }

    short8 ones;
    #pragma unroll
    for (int j = 0; j < 8; j++) ones[j] = (short)0x3F80;   // bf16 1.0

    for (int t = 0; t <= qt; t++) {
        __syncthreads();
        #pragma unroll
        for (int p = 0; p < 4; p++) {
            *(short8*)&Ks[p * 32 + krow][kcol] = kreg[p];
            *(short8*)&Vs[p * 16 + vrow][vcol] = vreg[p];
        }
        __syncthreads();

        // prefetch next tile into regs — waitcnt lands at next iteration's LDS write
        if (t < qt) {
            const int kb2 = (t + 1) * BKV;
            #pragma unroll
            for (int p = 0; p < 4; p++) {
                kreg[p] = *(const short8*)&kg[(size_t)(kb2 + p * 32 + krow) * 2048 + kcol];
                vreg[p] = *(const short8*)&vg[(size_t)(p * 16 + vrow) * S_LEN + kb2 + vcol];
            }
        }

        const bool diag = (t == qt);

        #pragma unroll
        for (int mi = 0; mi < 2; mi++) {
            // ---- S = Q K^T
            floatx4 sc[8];
            #pragma unroll
            for (int ns = 0; ns < 8; ns++) {
                const short8 kf0 = *(const short8*)&Ks[ns * 16 + l16][quad * 8];
                const short8 kf1 = *(const short8*)&Ks[ns * 16 + l16][32 + quad * 8];
                floatx4 z = {};
                z = __builtin_amdgcn_mfma_f32_16x16x32_bf16(qf[mi][0], kf0, z, 0, 0, 0);
                z = __builtin_amdgcn_mfma_f32_16x16x32_bf16(qf[mi][1], kf1, z, 0, 0, 0);
                sc[ns] = z;
            }

            // ---- scale + causal mask (diag tile only) + row max
            float mt[4];
            #pragma unroll
            for (int r = 0; r < 4; r++) {
                const int qloc = wave * 32 + mi * 16 + quad * 4 + r;   // row in [0,128)
                float mx = -1e30f;
                #pragma unroll
                for (int ns = 0; ns < 8; ns++) {
                    float v = sc[ns][r] * 0.125f;
                    if (diag) {
                        const int kj = ns * 16 + l16;
                        v = (kj <= qloc) ? v : -1e30f;
                    }
                    sc[ns][r] = v;
                    mx = fmaxf(mx, v);
                }
                mt[r] = mx;
            }
            #pragma unroll
            for (int off = 1; off < 16; off <<= 1)
                #pragma unroll
                for (int r = 0; r < 4; r++)
                    mt[r] = fmaxf(mt[r], __shfl_xor(mt[r], off, 64));

            // ---- exp + P store (C-layout -> per-wave LDS)
            float alpha[4];
            #pragma unroll
            for (int r = 0; r < 4; r++) {
                const float mnew = fmaxf(m_run[mi][r], mt[r]);
                alpha[r] = __expf(m_run[mi][r] - mnew);
                m_run[mi][r] = mnew;
                #pragma unroll
                for (int ns = 0; ns < 8; ns++)
                    Ps[wave][quad * 4 + r][ns * 16 + l16] = f2bf(__expf(sc[ns][r] - mnew));
            }

            // ---- P A-fragments (same-wave RAW through LDS, in-order DS)
            short8 pf[4];
            #pragma unroll
            for (int c = 0; c < 4; c++)
                pf[c] = *(const short8*)&Ps[wave][l16][c * 32 + quad * 8];

            // ---- row sums via MFMA: racc[r] = sum_k P[row][k] (same for all lanes)
            floatx4 racc = {};
            #pragma unroll
            for (int c = 0; c < 4; c++)
                racc = __builtin_amdgcn_mfma_f32_16x16x32_bf16(pf[c], ones, racc, 0, 0, 0);

            #pragma unroll
            for (int r = 0; r < 4; r++)
                l_run[mi][r] = l_run[mi][r] * alpha[r] + racc[r];

            #pragma unroll
            for (int d = 0; d < 4; d++)
                #pragma unroll
                for (int r = 0; r < 4; r++)
                    o_acc[mi][d][r] *= alpha[r];

            // ---- O += P V
            #pragma unroll
            for (int d = 0; d < 4; d++) {
                #pragma unroll
                for (int c = 0; c < 4; c++) {
                    const short8 vf = *(const short8*)&Vs[d * 16 + l16][c * 32 + quad * 8];
                    o_acc[mi][d] = __builtin_amdgcn_mfma_f32_16x16x32_bf16(pf[c], vf, o_acc[mi][d], 0, 0, 0);
                }
            }
        }
    }

    // ---- out[b, qi, h*64 + dh] = o / l
    #pragma unroll
    for (int mi = 0; mi < 2; mi++)
        #pragma unroll
        for (int r = 0; r < 4; r++) {
            const float inv = 1.0f / l_run[mi][r];
            const int qi = q0 + wave * 32 + mi * 16 + quad * 4 + r;
            #pragma unroll
            for (int d = 0; d < 4; d++)
                out[(size_t)(b * S_LEN + qi) * D_MODEL + h * DH + d * 16 + l16] =
                    f2bf(o_acc[mi][d][r] * inv);
        }
}

// ---------------------------------------------------------------------------
extern "C" void kernel_launch(void* const* d_in, const int* in_sizes, int n_in,
                              void* d_out, int out_size, void* d_ws, size_t ws_size,
                              hipStream_t stream)
{
    const float* x    = (const float*)d_in[0];
    const float* Wqkv = (const float*)d_in[1];
    const float* bqkv = (const float*)d_in[2];
    const float* Wo   = (const float*)d_in[3];
    const float* bo   = (const float*)d_in[4];
    float* out = (float*)d_out;

    ushort_t* xb    = (ushort_t*)d_ws;                       // N0
    ushort_t* wqkvb = xb + N0;                               // N1
    ushort_t* wob   = wqkvb + N1;                            // N2
    ushort_t* qkbuf = wob + N2;                              // 8192*2048
    ushort_t* vtbuf = qkbuf + (size_t)M_ROWS * 2048;         // B*NH*DH*S
    ushort_t* att   = vtbuf + (size_t)BATCH * NH * DH * S_LEN; // 8192*1024
    // total = 92.3 MB

    dim3 blk(256);
    cvt_f32_bf16<<<dim3((NQUADS + 255) / 256), blk, 0, stream>>>(x, Wqkv, Wo, xb, wqkvb, wob);
    // QKV projection: M=8192, N=3072, K=1024 -> qk (packed Q|K) + vt (V^T)
    gemm_bt_bias<false, true><<<dim3((3 * D_MODEL) / 128, M_ROWS / 128), blk, 0, stream>>>(
        xb, wqkvb, bqkv, qkbuf, vtbuf, M_ROWS, 3 * D_MODEL, D_MODEL);
    // causal attention (staged + prefetch)
    attn_causal<<<dim3(S_LEN / BQ, BATCH * NH), blk, 0, stream>>>(qkbuf, vtbuf, att);
    // output projection: M=8192, N=1024, K=1024 -> fp32 d_out
    gemm_bt_bias<true, false><<<dim3(D_MODEL / 128, M_ROWS / 128), blk, 0, stream>>>(
        att, wob, bo, out, nullptr, M_ROWS, D_MODEL, D_MODEL);
}

// Round 7
// 353.322 us; speedup vs baseline: 1.9006x; 1.1124x over previous
//
#include <hip/hip_runtime.h>

#define D_MODEL 1024
#define S_LEN   2048
#define BATCH   4
#define NH      16
#define DH      64
#define M_ROWS  (BATCH * S_LEN)   // 8192

typedef __attribute__((ext_vector_type(8))) short short8;
typedef __attribute__((ext_vector_type(4))) float floatx4;
typedef unsigned short ushort_t;
typedef __attribute__((ext_vector_type(4))) ushort_t ushortx4;

__device__ __forceinline__ ushort_t f2bf(float f) {
    union { float f; unsigned u; } v; v.f = f;
    unsigned r = v.u + 0x7FFFu + ((v.u >> 16) & 1u);
    return (ushort_t)(r >> 16);
}

// pack two f32 -> two bf16 (truncating) in one v_perm: low elem = lo, high = hi
__device__ __forceinline__ int pack2(float lo, float hi) {
    return (int)__builtin_amdgcn_perm(__float_as_uint(hi), __float_as_uint(lo), 0x07060302u);
}

// max over the 16 lanes of a DPP row (lanes 16q..16q+15) via row_ror — no LDS trip
__device__ __forceinline__ float rowmax16(float x) {
    float t;
    t = __int_as_float(__builtin_amdgcn_update_dpp(0, __float_as_int(x), 0x121, 0xf, 0xf, true)); x = fmaxf(x, t);
    t = __int_as_float(__builtin_amdgcn_update_dpp(0, __float_as_int(x), 0x122, 0xf, 0xf, true)); x = fmaxf(x, t);
    t = __int_as_float(__builtin_amdgcn_update_dpp(0, __float_as_int(x), 0x124, 0xf, 0xf, true)); x = fmaxf(x, t);
    t = __int_as_float(__builtin_amdgcn_update_dpp(0, __float_as_int(x), 0x128, 0xf, 0xf, true)); x = fmaxf(x, t);
    return x;
}

// async global->LDS, 16B/lane; LDS dest is wave-uniform base + lane*16
__device__ __forceinline__ void async_copy16(const ushort_t* g, ushort_t* l) {
    __builtin_amdgcn_global_load_lds(
        (const __attribute__((address_space(1))) void*)g,
        (__attribute__((address_space(3))) void*)l,
        16, 0, 0);
}

// ---------------------------------------------------------------------------
// fp32 -> bf16 downcast of x, W_qkv, W_o into workspace. 4 elems / thread.
// ---------------------------------------------------------------------------
#define N0 (M_ROWS * D_MODEL)        // x:      8,388,608
#define N1 (3 * D_MODEL * D_MODEL)   // W_qkv:  3,145,728
#define N2 (D_MODEL * D_MODEL)       // W_o:    1,048,576
#define NQUADS ((N0 + N1 + N2) / 4)

__global__ __launch_bounds__(256)
void cvt_f32_bf16(const float* __restrict__ s0, const float* __restrict__ s1,
                  const float* __restrict__ s2, ushort_t* __restrict__ d0,
                  ushort_t* __restrict__ d1, ushort_t* __restrict__ d2)
{
    const int q = blockIdx.x * 256 + threadIdx.x;
    if (q >= NQUADS) return;
    const float* s; ushort_t* d; int e;
    if (q < N0 / 4)            { s = s0; d = d0; e = q * 4; }
    else if (q < (N0 + N1) / 4){ s = s1; d = d1; e = q * 4 - N0; }
    else                       { s = s2; d = d2; e = q * 4 - N0 - N1; }
    const float4 v = *(const float4*)&s[e];
    ushortx4 o;
    o[0] = f2bf(v.x); o[1] = f2bf(v.y); o[2] = f2bf(v.z); o[3] = f2bf(v.w);
    *(ushortx4*)&d[e] = o;
}

// ---------------------------------------------------------------------------
// NT GEMM: C[M,N] = A[M,K] * B[N,K]^T + bias[N]. A,B bf16; bias fp32; fp32 acc.
// Staging via global_load_lds width=16 (m97 pattern): unpadded lane-linear LDS.
// VSPLIT (QKV gemm): cols [0,2048) -> qk[row*2048+col] bf16;
//                    cols [2048,3072) -> vt[b][h][dh][s] bf16 (V transposed).
// else: Cv with stride N, bf16 or fp32 per F32OUT.
// ---------------------------------------------------------------------------
template<bool F32OUT, bool VSPLIT>
__global__ __launch_bounds__(256)
void gemm_bt_bias(const ushort_t* __restrict__ A, const ushort_t* __restrict__ B,
                  const float* __restrict__ bias, void* __restrict__ Cv,
                  ushort_t* __restrict__ vt, int M, int N, int K)
{
    constexpr int BK = 32;
    __shared__ ushort_t As[128][BK];   // unpadded: 64B rows, lane-linear for DMA
    __shared__ ushort_t Bs[128][BK];

    const int tid  = threadIdx.x;
    const int lane = tid & 63;
    const int wave = tid >> 6;
    const int quad = lane >> 4;
    const int l16  = lane & 15;
    const int bm   = blockIdx.y * 128;
    const int bn   = blockIdx.x * 128;
    const int wm   = (wave & 1) * 64;
    const int wn   = (wave >> 1) * 64;

    floatx4 acc[4][4] = {};

    // DMA map: instr covers 16 rows; lane ℓ -> row ℓ>>2, col (ℓ&3)*8 elems
    const int srow = lane >> 2;
    const int scol = (lane & 3) * 8;

    for (int k0 = 0; k0 < K; k0 += BK) {
        __syncthreads();
        #pragma unroll
        for (int h = 0; h < 2; h++) {
            const int r0 = wave * 32 + h * 16;
            async_copy16(&A[(size_t)(bm + r0 + srow) * K + k0 + scol], &As[r0][0]);
            async_copy16(&B[(size_t)(bn + r0 + srow) * K + k0 + scol], &Bs[r0][0]);
        }
        __syncthreads();

        short8 af[4], bfr[4];
        #pragma unroll
        for (int i = 0; i < 4; i++) af[i]  = *(const short8*)&As[wm + i * 16 + l16][quad * 8];
        #pragma unroll
        for (int i = 0; i < 4; i++) bfr[i] = *(const short8*)&Bs[wn + i * 16 + l16][quad * 8];

        #pragma unroll
        for (int mi = 0; mi < 4; mi++)
            #pragma unroll
            for (int ni = 0; ni < 4; ni++)
                acc[mi][ni] = __builtin_amdgcn_mfma_f32_16x16x32_bf16(af[mi], bfr[ni], acc[mi][ni], 0, 0, 0);
    }

    // Epilogue: C/D layout col = lane&15, row = quad*4 + reg
    #pragma unroll
    for (int ni = 0; ni < 4; ni++) {
        const int col = bn + wn + ni * 16 + l16;
        const float bv = bias[col];
        #pragma unroll
        for (int mi = 0; mi < 4; mi++)
            #pragma unroll
            for (int r = 0; r < 4; r++) {
                const int row = bm + wm + mi * 16 + quad * 4 + r;
                const float val = acc[mi][ni][r] + bv;
                if (VSPLIT) {
                    if (col < 2 * D_MODEL) {   // block-uniform branch
                        ((ushort_t*)Cv)[(size_t)row * 2048 + col] = f2bf(val);
                    } else {
                        const int vcol = col - 2 * D_MODEL;
                        const int h = vcol >> 6, dh = vcol & 63;
                        const int b = row >> 11, s = row & 2047;
                        vt[(((size_t)(b * NH + h)) * DH + dh) * S_LEN + s] = f2bf(val);
                    }
                } else if (F32OUT) {
                    ((float*)Cv)[(size_t)row * N + col] = val;
                } else {
                    ((ushort_t*)Cv)[(size_t)row * N + col] = f2bf(val);
                }
            }
    }
}

// ---------------------------------------------------------------------------
// Causal flash attention. qk: [B,S,2048] (Q|K packed bf16). vt: [B,H,DH,S].
// Block = one (b,h) x 128 q rows; 4 waves x 32 q rows (2 m-frags sequential);
// BKV=128 key tiles, register-prefetch pipeline.
// Softmax in exp2-domain; row max via DPP (no LDS shuffles); P packed with
// v_perm (truncating) into position-permuted layout pos(k)=(k&15)*8+(k>>4),
// written as one ds_write_b128 per row. V staged with the same permutation so
// PV's A/B k-ordering matches (dot products permutation-invariant).
// Row sums via MFMA against a ones-fragment. out: [B,S,D_MODEL] bf16.
// ---------------------------------------------------------------------------
#define BQ  128
#define BKV 128

__global__ __launch_bounds__(256, 2)
void attn_causal(const ushort_t* __restrict__ qk, const ushort_t* __restrict__ vt,
                 ushort_t* __restrict__ out)
{
    __shared__ ushort_t Ks[BKV][DH + 8];      // [key][dh]        (18.4 KB)
    __shared__ ushort_t Vs[DH][BKV + 8];      // [dh][pos]        (17.4 KB)
    __shared__ ushort_t Ps[4][16][BKV + 8];   // per-wave [row][pos] (17.4 KB)

    const int tid  = threadIdx.x;
    const int lane = tid & 63;
    const int wave = tid >> 6;
    const int quad = lane >> 4;
    const int l16  = lane & 15;

    const int qt = (int)gridDim.x - 1 - (int)blockIdx.x;   // heavy blocks first (LPT)
    const int bh = blockIdx.y;
    const int b  = bh >> 4;
    const int h  = bh & 15;
    const int q0 = qt * BQ;

    const float C2 = 0.18033688011112042f;   // 0.125 * log2(e)

    const size_t qkbase = (size_t)b * S_LEN * 2048;

    // Q A-fragments straight from global: A[m=l16][k=quad*8+j]
    short8 qf[2][2];
    #pragma unroll
    for (int mi = 0; mi < 2; mi++) {
        const ushort_t* qp = qk + qkbase + (size_t)(q0 + wave * 32 + mi * 16 + l16) * 2048 + h * DH;
        qf[mi][0] = *(const short8*)(qp + quad * 8);
        qf[mi][1] = *(const short8*)(qp + 32 + quad * 8);
    }

    const ushort_t* kg = qk + qkbase + D_MODEL + h * DH;            // + key*2048
    const ushort_t* vg = vt + (size_t)(b * NH + h) * DH * S_LEN;    // + dh*S + key

    // staging map: K 8 thr/row (128B), V 16 thr/row (256B) — coalesced global reads
    const int krow = tid >> 3, kcol = (tid & 7) * 8;
    const int vrow = tid >> 4, vcol = (tid & 15) * 8;
    const int vposb = ((vcol & 15) << 3) + (vcol >> 4);   // pos of vcol (vcol..vcol+7 -> +j*8)

    short8 kreg[4], vreg[4];
    #pragma unroll
    for (int p = 0; p < 4; p++) {
        kreg[p] = *(const short8*)&kg[(size_t)(p * 32 + krow) * 2048 + kcol];
        vreg[p] = *(const short8*)&vg[(size_t)(p * 16 + vrow) * S_LEN + vcol];
    }

    float m_run[2][4], l_run[2][4];
    floatx4 o_acc[2][4] = {};
    #pragma unroll
    for (int mi = 0; mi < 2; mi++)
        #pragma unroll
        for (int r = 0; r < 4; r++) { m_run[mi][r] = -1e30f; l_run[mi][r] = 0.f; }

    short8 ones;
    #pragma unroll
    for (int j = 0; j < 8; j++) ones[j] = (short)0x3F80;   // bf16 1.0

    for (int t = 0; t <= qt; t++) {
        __syncthreads();
        #pragma unroll
        for (int p = 0; p < 4; p++) {
            *(short8*)&Ks[p * 32 + krow][kcol] = kreg[p];
            #pragma unroll
            for (int j = 0; j < 8; j++)        // position-permuted scatter
                Vs[p * 16 + vrow][vposb + j * 8] = (ushort_t)vreg[p][j];
        }
        __syncthreads();

        // prefetch next tile into regs — latency hidden behind this tile's compute
        if (t < qt) {
            const int kb2 = (t + 1) * BKV;
            #pragma unroll
            for (int p = 0; p < 4; p++) {
                kreg[p] = *(const short8*)&kg[(size_t)(kb2 + p * 32 + krow) * 2048 + kcol];
                vreg[p] = *(const short8*)&vg[(size_t)(p * 16 + vrow) * S_LEN + kb2 + vcol];
            }
        }

        const bool diag = (t == qt);

        #pragma unroll
        for (int mi = 0; mi < 2; mi++) {
            // ---- S = Q K^T
            floatx4 sc[8];
            #pragma unroll
            for (int ns = 0; ns < 8; ns++) {
                const short8 kf0 = *(const short8*)&Ks[ns * 16 + l16][quad * 8];
                const short8 kf1 = *(const short8*)&Ks[ns * 16 + l16][32 + quad * 8];
                floatx4 z = {};
                z = __builtin_amdgcn_mfma_f32_16x16x32_bf16(qf[mi][0], kf0, z, 0, 0, 0);
                z = __builtin_amdgcn_mfma_f32_16x16x32_bf16(qf[mi][1], kf1, z, 0, 0, 0);
                sc[ns] = z;
            }

            // ---- exp2-domain scale + causal mask (diag only) + DPP row max
            float mt[4];
            #pragma unroll
            for (int r = 0; r < 4; r++) {
                const int qloc = wave * 32 + mi * 16 + quad * 4 + r;
                float mx = -1e30f;
                #pragma unroll
                for (int ns = 0; ns < 8; ns++) {
                    float v = sc[ns][r] * C2;
                    if (diag) {
                        const int kj = ns * 16 + l16;
                        v = (kj <= qloc) ? v : -1e30f;
                    }
                    sc[ns][r] = v;
                    mx = fmaxf(mx, v);
                }
                mt[r] = rowmax16(mx);
            }

            // ---- online update + exp2 + v_perm pack + one b128 write per row
            float alpha[4];
            #pragma unroll
            for (int r = 0; r < 4; r++) {
                const float mnew = fmaxf(m_run[mi][r], mt[r]);
                alpha[r] = __builtin_amdgcn_exp2f(m_run[mi][r] - mnew);
                m_run[mi][r] = mnew;
                float p[8];
                #pragma unroll
                for (int ns = 0; ns < 8; ns++)
                    p[ns] = __builtin_amdgcn_exp2f(sc[ns][r] - mnew);
                int4 w;
                w.x = pack2(p[0], p[1]);
                w.y = pack2(p[2], p[3]);
                w.z = pack2(p[4], p[5]);
                w.w = pack2(p[6], p[7]);
                *(int4*)&Ps[wave][quad * 4 + r][l16 * 8] = w;
            }

            // ---- P A-fragments (same-wave RAW through LDS, in-order DS)
            short8 pf[4];
            #pragma unroll
            for (int c = 0; c < 4; c++)
                pf[c] = *(const short8*)&Ps[wave][l16][c * 32 + quad * 8];

            // ---- row sums via MFMA (sum over k, permutation-invariant)
            floatx4 racc = {};
            #pragma unroll
            for (int c = 0; c < 4; c++)
                racc = __builtin_amdgcn_mfma_f32_16x16x32_bf16(pf[c], ones, racc, 0, 0, 0);

            #pragma unroll
            for (int r = 0; r < 4; r++)
                l_run[mi][r] = l_run[mi][r] * alpha[r] + racc[r];

            #pragma unroll
            for (int d = 0; d < 4; d++)
                #pragma unroll
                for (int r = 0; r < 4; r++)
                    o_acc[mi][d][r] *= alpha[r];

            // ---- O += P V (Vs is position-permuted to match P)
            #pragma unroll
            for (int d = 0; d < 4; d++) {
                #pragma unroll
                for (int c = 0; c < 4; c++) {
                    const short8 vf = *(const short8*)&Vs[d * 16 + l16][c * 32 + quad * 8];
                    o_acc[mi][d] = __builtin_amdgcn_mfma_f32_16x16x32_bf16(pf[c], vf, o_acc[mi][d], 0, 0, 0);
                }
            }
        }
    }

    // ---- out[b, qi, h*64 + dh] = o / l
    #pragma unroll
    for (int mi = 0; mi < 2; mi++)
        #pragma unroll
        for (int r = 0; r < 4; r++) {
            const float inv = 1.0f / l_run[mi][r];
            const int qi = q0 + wave * 32 + mi * 16 + quad * 4 + r;
            #pragma unroll
            for (int d = 0; d < 4; d++)
                out[(size_t)(b * S_LEN + qi) * D_MODEL + h * DH + d * 16 + l16] =
                    f2bf(o_acc[mi][d][r] * inv);
        }
}

// ---------------------------------------------------------------------------
extern "C" void kernel_launch(void* const* d_in, const int* in_sizes, int n_in,
                              void* d_out, int out_size, void* d_ws, size_t ws_size,
                              hipStream_t stream)
{
    const float* x    = (const float*)d_in[0];
    const float* Wqkv = (const float*)d_in[1];
    const float* bqkv = (const float*)d_in[2];
    const float* Wo   = (const float*)d_in[3];
    const float* bo   = (const float*)d_in[4];
    float* out = (float*)d_out;

    ushort_t* xb    = (ushort_t*)d_ws;                       // N0
    ushort_t* wqkvb = xb + N0;                               // N1
    ushort_t* wob   = wqkvb + N1;                            // N2
    ushort_t* qkbuf = wob + N2;                              // 8192*2048
    ushort_t* vtbuf = qkbuf + (size_t)M_ROWS * 2048;         // B*NH*DH*S
    ushort_t* att   = vtbuf + (size_t)BATCH * NH * DH * S_LEN; // 8192*1024
    // total = 92.3 MB

    dim3 blk(256);
    cvt_f32_bf16<<<dim3((NQUADS + 255) / 256), blk, 0, stream>>>(x, Wqkv, Wo, xb, wqkvb, wob);
    // QKV projection: M=8192, N=3072, K=1024 -> qk (packed Q|K) + vt (V^T)
    gemm_bt_bias<false, true><<<dim3((3 * D_MODEL) / 128, M_ROWS / 128), blk, 0, stream>>>(
        xb, wqkvb, bqkv, qkbuf, vtbuf, M_ROWS, 3 * D_MODEL, D_MODEL);
    // causal attention
    attn_causal<<<dim3(S_LEN / BQ, BATCH * NH), blk, 0, stream>>>(qkbuf, vtbuf, att);
    // output projection: M=8192, N=1024, K=1024 -> fp32 d_out
    gemm_bt_bias<true, false><<<dim3(D_MODEL / 128, M_ROWS / 128), blk, 0, stream>>>(
        att, wob, bo, out, nullptr, M_ROWS, D_MODEL, D_MODEL);
}